// Round 5
// baseline (1009.032 us; speedup 1.0000x reference)
//
#include <hip/hip_runtime.h>
#include <cstdint>

// LSTM: B=1024, T=336, I=64, H=256, gates 4H=1024, K = I+H = 320.
// R10: fan-in-1 partition. 128 batch-groups x 2 member-WGs = 256 WGs (1/CU),
// 8 batches/group, each member owns 128 gate-cols (x4 gates). Per step:
//   stage x -> barrier1 -> ISSUE partner poll loads (asm, no wait)
//   -> phase-1 MFMA over 6 LOCAL k-tiles (x0,x1, own-h x4)  [~400+ cyc cover]
//   -> vmcnt(0) + tag check (first check should HIT; pipelined retry else)
//   -> barrier2 -> phase-2 MFMA over 4 remote tiles -> cell -> store.
// vs R9 (M=4): fan-in 3->1 (R8 showed tail-of-N is the cost), local phase
// 4->6 tiles of 10 (R9's phase-1 was too short to hide the L3 round trip),
// poll issued EARLY so the round trip overlaps phase-1 instead of spinning
// (VALUBusy 37% was poll-spin). MFMA/wave doubles (batch 8/16 lanes idle) --
// cheap vs the spin it removes. Lanes l15>=8 masked on stores, B-reads
// clamped (l15&7). Exchange stays proven device-scope sc0+sc1.

#define NGROUP  128
#define BATCH_G 8
#define T_STEPS 336
#define I_DIM   64
#define H_DIM   256
#define VSTRIDE 336   // ushorts per staged row: K=320 + 16 pad (672 B, 16B-aligned)
#define PAIRS   128   // h-pairs per batch row (256 cols / 2)
#define OUT_HALF 262144  // 1024*256

typedef __attribute__((ext_vector_type(8))) __bf16 bf16x8;
typedef __attribute__((ext_vector_type(8))) unsigned short ushort8_t;
typedef __attribute__((ext_vector_type(4))) float f32x4;
typedef __attribute__((ext_vector_type(4))) unsigned uint32x4;
typedef __attribute__((ext_vector_type(2))) unsigned uint32x2;

__device__ inline unsigned short f2bf(float f) {
  unsigned u = __builtin_bit_cast(unsigned, f);
  return (unsigned short)((u + 0x7fffu + ((u >> 16) & 1u)) >> 16);
}
__device__ inline float sigf(float x) { return 1.f / (1.f + __expf(-x)); }
__device__ inline float tanhfast(float x) { return 1.f - 2.f / (1.f + __expf(2.f * x)); }

// slot s (0..9) -> k-tile kt (0..9). 0,1 = x tiles; 2..5 = own h (4 tiles at
// kt = 2+4*mid ..); 6..9 = partner h (kt = 2+4*(1-mid) ..).
__device__ inline int slot_kt(int s, int mid) {
  return (s < 2) ? s
       : (s < 6) ? (2 + 4 * mid + (s - 2))
       : (2 + 4 * (1 - mid) + (s - 6));
}

__device__ inline void st_pair(uint32x2* p, uint32x2 v) {
  asm volatile("global_store_dwordx2 %0, %1, off sc0 sc1" :: "v"(p), "v"(v) : "memory");
}

__global__ __launch_bounds__(512, 2) void lstm_persistent(
    const float* __restrict__ x, const float* __restrict__ W_ih,
    const float* __restrict__ W_hh, const float* __restrict__ b_ih,
    const float* __restrict__ b_hh, float* __restrict__ out,
    uint32x2* __restrict__ hbuf)
{
  __shared__ __align__(16) unsigned short v_lds[2][BATCH_G * VSTRIDE];

  const int tid  = threadIdx.x;
  const int gid  = blockIdx.x & (NGROUP - 1);   // batch group (8 batches)
  const int mid  = blockIdx.x >> 7;             // member 0..1 (cols [mid*128, +128))
  const int wv   = tid >> 6;                    // wave 0..7
  const int l    = tid & 63;
  const int l15  = l & 15, quad = l >> 4;
  const int rg   = wv;                          // wave owns cols [mid*128+rg*16, +16)

  // ---- A-fragments in SLOT order; wave holds 4 row-tiles x 10 k-tiles ----
  bf16x8 afrag[4][10];
#pragma unroll
  for (int rt = 0; rt < 4; ++rt) {
    int grow = (l15 & 3) * H_DIM + mid * 128 + rg * 16 + rt * 4 + (l15 >> 2);
    const float* wih_row = W_ih + (long)grow * I_DIM;
    const float* whh_row = W_hh + (long)grow * H_DIM;
#pragma unroll
    for (int s = 0; s < 10; ++s) {
      int kt = slot_kt(s, mid);
      int kbase = kt * 32 + quad * 8;
      ushort8_t a;
#pragma unroll
      for (int e = 0; e < 8; ++e) {
        int k = kbase + e;
        float v = (k < I_DIM) ? wih_row[k] : whh_row[k - I_DIM];
        a[e] = f2bf(v);
      }
      afrag[rt][s] = __builtin_bit_cast(bf16x8, a);
    }
  }

  // ---- bias as acc-init: lane's cell = (col = rg*16+rt*4+quad, batch = l15) ----
  f32x4 bias[4];
#pragma unroll
  for (int rt = 0; rt < 4; ++rt) {
#pragma unroll
    for (int g = 0; g < 4; ++g) {
      int grow = g * H_DIM + mid * 128 + rg * 16 + rt * 4 + quad;
      bias[rt][g] = b_ih[grow] + b_hh[grow];
    }
  }

  const int  batch = l15;            // 0..15; only 0..7 valid
  const bool bok   = (l15 < 8);
  float c_reg[4] = {0.f, 0.f, 0.f, 0.f};
  float h_keep[4];

  // ---- x staging: 64 threads per batch row (1 float each) ----
  const int b_stage = tid >> 6;          // 0..7
  const int x_if    = tid & 63;
  const float* xrow = x + ((long)(gid * BATCH_G + b_stage)) * T_STEPS * I_DIM + x_if;

  // ---- consumer: thread owns ONE partner entry (pair_r, batch_ld) = 8 B ----
  const int pair_r   = tid >> 3;         // 0..63 (partner-relative pair)
  const int batch_ld = tid & 7;
  const uint32x2* ld_src = hbuf + ((long)gid * PAIRS + (1 - mid) * 64 + pair_r) * BATCH_G + batch_ld;

  // ---- producer: pair = mid*64 + rg*8 + rt*2 + (quad>>1), batch = l15 ----
  uint32x2* st_base = hbuf + ((long)gid * PAIRS + mid * 64 + rg * 8 + (quad >> 1)) * BATCH_G + batch;
  const long buf_stride = (long)NGROUP * PAIRS * BATCH_G;

  // ---- pre-zero full h region of buffer 1 (t=1 reads zeros; no polling) ----
  {
    int zr = tid >> 6, zc = (tid & 63) * 4;
    uint32x2 z; z[0] = 0u; z[1] = 0u;
    *(uint32x2*)&v_lds[1][zr * VSTRIDE + I_DIM + zc] = z;
  }

  // ---- x prefetch one step ahead ----
  float xv = *xrow;   // row for t=1

  for (int t = 1; t <= T_STEPS; ++t) {
    unsigned short* vbuf = v_lds[t & 1];

    // ---- stage prefetched x_t, then issue the next row's load ----
    vbuf[b_stage * VSTRIDE + x_if] = f2bf(xv);
    if (t < T_STEPS) xv = xrow[(long)t * I_DIM];

    __syncthreads();   // barrier1: x_t + own-h (from prev epilogue) visible

    // ---- issue partner poll load EARLY (overlaps phase-1 MFMA) ----
    uint32x2 pl;
    const uint32x2* hsrc = ld_src + ((t - 1) & 1) * buf_stride;
    if (t > 1)
      asm volatile("global_load_dwordx2 %0, %1, off sc0 sc1"
                   : "=v"(pl) : "v"(hsrc) : "memory");

    // ---- phase 1: 6 local tiles (x0, x1, own-h x4) = 24 MFMA/wave ----
    f32x4 acc[4] = {bias[0], bias[1], bias[2], bias[3]};
    const unsigned short* vb = vbuf + (unsigned)(l15 & 7) * VSTRIDE + quad * 8;
#pragma unroll
    for (int s = 0; s < 6; ++s) {
      int kt = slot_kt(s, mid);
      bf16x8 bv = __builtin_bit_cast(bf16x8, *(const uint32x4*)(vb + kt * 32));
#pragma unroll
      for (int rt = 0; rt < 4; ++rt)
        acc[rt] = __builtin_amdgcn_mfma_f32_16x16x32_bf16(afrag[rt][s], bv, acc[rt], 0, 0, 0);
    }

    // ---- check poll result (round trip hidden behind phase-1) ----
    if (t > 1) {
      asm volatile("s_waitcnt vmcnt(0)" ::: "memory");
      __builtin_amdgcn_sched_barrier(0);
      const unsigned tag = (unsigned)(t - 1);
      int it = 0;
      while (pl[0] != tag) {
        if (++it > (1 << 17)) break;   // safety valve vs. hang
        __builtin_amdgcn_s_sleep(1);
        asm volatile("global_load_dwordx2 %0, %1, off sc0 sc1\n\t"
                     "s_waitcnt vmcnt(0)"
                     : "=v"(pl) : "v"(hsrc) : "memory");
        __builtin_amdgcn_sched_barrier(0);
      }
      // stage partner h pair into this batch row
      *(unsigned*)&vbuf[(unsigned)batch_ld * VSTRIDE + I_DIM + (1 - mid) * 128 + 2 * pair_r] = pl[1];
    }
    __syncthreads();   // barrier2: remote h staged

    // ---- phase 2: 4 remote tiles = 16 MFMA/wave ----
#pragma unroll
    for (int s = 6; s < 10; ++s) {
      int kt = slot_kt(s, mid);
      bf16x8 bv = __builtin_bit_cast(bf16x8, *(const uint32x4*)(vb + kt * 32));
#pragma unroll
      for (int rt = 0; rt < 4; ++rt)
        acc[rt] = __builtin_amdgcn_mfma_f32_16x16x32_bf16(afrag[rt][s], bv, acc[rt], 0, 0, 0);
    }

    // ---- cell in registers; own-slice to LDS; tagged pair to partner ----
    __builtin_amdgcn_s_setprio(1);
    unsigned short* next_own = v_lds[(t + 1) & 1] + (unsigned)batch * VSTRIDE + I_DIM + mid * 128;
#pragma unroll
    for (int rt = 0; rt < 4; ++rt) {
      float cc = sigf(acc[rt][1]) * c_reg[rt] + sigf(acc[rt][0]) * tanhfast(acc[rt][2]);
      float h  = sigf(acc[rt][3]) * tanhfast(cc);
      c_reg[rt] = cc; h_keep[rt] = h;
      unsigned short hb16 = f2bf(h);
      unsigned hb = (unsigned)hb16;
      unsigned prt = (unsigned)__shfl_xor((int)hb, 16, 64);   // col^1, same batch
      if (bok) {
        next_own[rg * 16 + rt * 4 + quad] = hb16;             // LDS shortcut (own WG)
        if (!(quad & 1)) {
          uint32x2 pv;
          pv[0] = (unsigned)t;                  // tag
          pv[1] = hb | (prt << 16);             // (col, col+1)
          st_pair(st_base + rt * 2 * BATCH_G + (t & 1) * buf_stride, pv);  // fire-and-forget
        }
      }
    }
    __builtin_amdgcn_s_setprio(0);
  }

  // ---- outputs: h_T then c_T, fp32 (pre-bf16-rounding values) ----
#pragma unroll
  for (int rt = 0; rt < 4; ++rt) {
    if (bok) {
      int gcol = mid * 128 + rg * 16 + rt * 4 + quad;
      long o = (long)(gid * BATCH_G + batch) * H_DIM + gcol;
      out[o]            = h_keep[rt];
      out[OUT_HALF + o] = c_reg[rt];
    }
  }
}

extern "C" void kernel_launch(void* const* d_in, const int* in_sizes, int n_in,
                              void* d_out, int out_size, void* d_ws, size_t ws_size,
                              hipStream_t stream) {
  const float* x    = (const float*)d_in[0];
  const float* W_ih = (const float*)d_in[1];
  const float* W_hh = (const float*)d_in[2];
  const float* b_ih = (const float*)d_in[3];
  const float* b_hh = (const float*)d_in[4];
  float* out = (float*)d_out;

  uint32x2* hbuf = (uint32x2*)d_ws;   // 2 bufs x 128 groups x 128 pairs x 8 batch x 8 B = 2 MB

  // Clear tags so no stale value can match t in [1,336].
  hipMemsetAsync(d_ws, 0, 2u * NGROUP * PAIRS * BATCH_G * 8u, stream);
  lstm_persistent<<<dim3(256), dim3(512), 0, stream>>>(x, W_ih, W_hh, b_ih, b_hh, out, hbuf);
}

// Round 7
// 963.767 us; speedup vs baseline: 1.0470x; 1.0470x over previous
//
#include <hip/hip_runtime.h>
#include <cstdint>

// LSTM: B=1024, T=336, I=64, H=256, gates 4H=1024, K = I+H = 320.
// R11: R9 structure (64 groups x 4 members, 16 batches/group, 64 cols/member,
// split-phase MFMA, verified 738us) + CROSS-STEP SPECULATIVE POLL:
// the partner's store for tag t is issued during its epilogue of step t,
// which in lockstep coincides with OUR epilogue of step t. So we issue the
// poll loads for tag t at the END of our step t (fire-and-forget into
// persistent registers), and check them after phase-1 of step t+1 -- the
// x-stage + barrier + phase-1 (~400-600cyc) covers the L3 round trip, and
// the snapshot is taken well after the store landed. First check should hit
// in steady state (R10 showed issuing after barrier1 snapshots too early).
// Miss -> R9's bounded poll loop as fallback (correctness unchanged: tag
// check gates everything). R10's M=2 regression reverted (doubled MFMA +
// half-sector writes). Exchange stays proven device-scope sc0+sc1.

#define NGROUP  64
#define BATCH_G 16
#define T_STEPS 336
#define I_DIM   64
#define H_DIM   256
#define VSTRIDE 336   // ushorts per staged row: K=320 + 16 pad (672 B, 16B-aligned)
#define PAIRS   128   // h-pairs per batch row (256 cols / 2)
#define OUT_HALF 262144  // 1024*256

typedef __attribute__((ext_vector_type(8))) __bf16 bf16x8;
typedef __attribute__((ext_vector_type(8))) unsigned short ushort8_t;
typedef __attribute__((ext_vector_type(4))) float f32x4;
typedef __attribute__((ext_vector_type(4))) unsigned uint32x4;
typedef __attribute__((ext_vector_type(2))) unsigned uint32x2;

__device__ inline unsigned short f2bf(float f) {
  unsigned u = __builtin_bit_cast(unsigned, f);
  return (unsigned short)((u + 0x7fffu + ((u >> 16) & 1u)) >> 16);
}
__device__ inline float sigf(float x) { return 1.f / (1.f + __expf(-x)); }
__device__ inline float tanhfast(float x) { return 1.f - 2.f / (1.f + __expf(2.f * x)); }

// slot s (0..9) -> k-tile index kt (0..9). Slots 0,1 = x tiles; 2,3 = own h
// tiles (kt = 2+2*mid, 3+2*mid); 4..9 = the 6 remote h tiles in kt order.
__device__ inline int slot_kt(int s, int mid) {
  return (s < 2) ? s
       : (s < 4) ? (2 + 2 * mid + (s - 2))
       : (((s - 4) < 2 * mid) ? (s - 2) : s);
}

// 2 concurrent coherent 16B loads (4 tagged pairs = 32B contiguous), one round trip.
__device__ inline void ld2_tagged(const uint32x2* p, uint32x4& a, uint32x4& b) {
  asm volatile(
      "global_load_dwordx4 %0, %2, off sc0 sc1\n\t"
      "global_load_dwordx4 %1, %3, off sc0 sc1\n\t"
      "s_waitcnt vmcnt(0)"
      : "=&v"(a), "=&v"(b)
      : "v"(p), "v"(p + 2)
      : "memory");
}
__device__ inline void st_pair(uint32x2* p, uint32x2 v) {
  asm volatile("global_store_dwordx2 %0, %1, off sc0 sc1" :: "v"(p), "v"(v) : "memory");
}

// Starting from pre-loaded A/Bv, retry until tag matches, then scatter.
__device__ inline void stage_from(uint32x4 A, uint32x4 Bv, const uint32x2* hsrc,
                                  unsigned tag, unsigned short* hdst) {
  int it = 0;
  while (!((A[0] == tag) & (A[2] == tag) & (Bv[0] == tag) & (Bv[2] == tag))) {
    if (++it > (1 << 17)) break;   // safety valve vs. hang
    __builtin_amdgcn_s_sleep(1);
    ld2_tagged(hsrc, A, Bv);
  }
  *(unsigned*)(hdst + 0 * VSTRIDE) = A[1];
  *(unsigned*)(hdst + 1 * VSTRIDE) = A[3];
  *(unsigned*)(hdst + 2 * VSTRIDE) = Bv[1];
  *(unsigned*)(hdst + 3 * VSTRIDE) = Bv[3];
}

__global__ __launch_bounds__(512, 2) void lstm_persistent(
    const float* __restrict__ x, const float* __restrict__ W_ih,
    const float* __restrict__ W_hh, const float* __restrict__ b_ih,
    const float* __restrict__ b_hh, float* __restrict__ out,
    uint32x2* __restrict__ hbuf)
{
  __shared__ __align__(16) unsigned short v_lds[2][BATCH_G * VSTRIDE];

  const int tid  = threadIdx.x;
  const int gid  = blockIdx.x & 63;   // batch group (16 batches)
  const int mid  = blockIdx.x >> 6;   // member 0..3 (owns gate cols [mid*64, +64))
  const int wv   = tid >> 6;          // wave 0..7
  const int l    = tid & 63;
  const int l15  = l & 15, quad = l >> 4;
  const int rg   = wv;                // row-group 0..7: local cols [8*rg, +8)

  // ---- A-fragments in SLOT order (0,1=x; 2,3=own h; 4..9=remote h) ----
  bf16x8 afrag[2][10];
#pragma unroll
  for (int rt = 0; rt < 2; ++rt) {
    int grow = (l15 & 3) * H_DIM + mid * 64 + rg * 8 + rt * 4 + (l15 >> 2);
    const float* wih_row = W_ih + (long)grow * I_DIM;
    const float* whh_row = W_hh + (long)grow * H_DIM;
#pragma unroll
    for (int s = 0; s < 10; ++s) {
      int kt = slot_kt(s, mid);
      int kbase = kt * 32 + quad * 8;
      ushort8_t a;
#pragma unroll
      for (int e = 0; e < 8; ++e) {
        int k = kbase + e;
        float v = (k < I_DIM) ? wih_row[k] : whh_row[k - I_DIM];
        a[e] = f2bf(v);
      }
      afrag[rt][s] = __builtin_bit_cast(bf16x8, a);
    }
  }

  // ---- bias as acc-init: lane's cell = (col = rg*8+rt*4+quad, batch = l15) ----
  f32x4 bias[2];
#pragma unroll
  for (int rt = 0; rt < 2; ++rt) {
#pragma unroll
    for (int g = 0; g < 4; ++g) {
      int grow = g * H_DIM + mid * 64 + rg * 8 + rt * 4 + quad;
      bias[rt][g] = b_ih[grow] + b_hh[grow];
    }
  }

  const int batch = l15;              // 0..15 within group
  float c_reg[2] = {0.f, 0.f};
  float h_keep[2];

  // ---- x staging: 32 threads per batch row (float2 each) ----
  const int b_stage = tid >> 5;          // 0..15
  const int x_i2    = (tid & 31) * 2;    // 2 floats of x
  const float* xrow = x + ((long)(gid * BATCH_G + b_stage)) * T_STEPS * I_DIM + x_i2;

  // ---- h staging (consumer): thread owns pair p_ld, batches b0_ld..b0_ld+3
  //      = 32 B contiguous aligned in pair-major hbuf. Waves 2*mid, 2*mid+1
  //      skip polling (own slice arrives via LDS shortcut). ----
  const int p_ld  = tid >> 2;            // 0..127
  const int b0_ld = (tid & 3) * 4;       // 0,4,8,12
  const uint32x2* ld_base = hbuf + ((long)gid * PAIRS + p_ld) * BATCH_G + b0_ld;

  // ---- producer store: pair = mid*32 + rg*4 + rt*2 + (quad>>1), batch = l15
  //      -> lanes l15 contiguous => 128 B runs, full sectors. ----
  uint32x2* st_base = hbuf + ((long)gid * PAIRS + mid * 32 + rg * 4 + (quad >> 1)) * BATCH_G + batch;
  const long buf_stride = (long)NGROUP * PAIRS * BATCH_G;
  const bool own_wave = ((wv >> 1) == mid);

  // ---- pre-zero h region of buffer 1 (t=1 reads zeros; no polling at t=1).
  //      512 threads x 16 B == 16 rows x 512 B exactly. ----
  {
    int zr = tid >> 5, zc = (tid & 31) * 8;
    uint32x4 z = {0u, 0u, 0u, 0u};
    *(uint32x4*)&v_lds[1][zr * VSTRIDE + I_DIM + zc] = z;
  }

  // ---- x prefetch one step ahead (HBM latency off the critical path) ----
  float2 xv = *(const float2*)xrow;     // row for t=1

  // ---- speculative poll registers (issued end of step t, checked at t+1) ----
  uint32x4 spA, spB;

  for (int t = 1; t <= T_STEPS; ++t) {
    unsigned short* vbuf = v_lds[t & 1];

    // ---- stage prefetched x_t, then issue the next row's load ----
    {
      ushort2 xb;
      xb.x = f2bf(xv.x); xb.y = f2bf(xv.y);
      *(ushort2*)&vbuf[b_stage * VSTRIDE + x_i2] = xb;
    }
    if (t < T_STEPS) xv = *(const float2*)(xrow + (long)t * I_DIM);

    __syncthreads();   // barrier1: x_t + own-h (from prev epilogue) visible

    // ---- phase 1: local tiles (x0, x1, own-h0, own-h1) ----
    f32x4 acc0 = bias[0], acc1 = bias[1];
    const unsigned short* vb = vbuf + (unsigned)batch * VSTRIDE + quad * 8;
#pragma unroll
    for (int s = 0; s < 4; ++s) {
      int kt = slot_kt(s, mid);
      bf16x8 bv = __builtin_bit_cast(bf16x8, *(const uint32x4*)(vb + kt * 32));
      acc0 = __builtin_amdgcn_mfma_f32_16x16x32_bf16(afrag[0][s], bv, acc0, 0, 0, 0);
      acc1 = __builtin_amdgcn_mfma_f32_16x16x32_bf16(afrag[1][s], bv, acc1, 0, 0, 0);
    }

    // ---- check speculative poll (issued end of step t-1; round trip fully
    //      hidden behind our epilogue + x-stage + barrier + phase-1) ----
    if (t > 1 && !own_wave) {
      asm volatile("s_waitcnt vmcnt(0)" ::: "memory");
      __builtin_amdgcn_sched_barrier(0);
      unsigned short* hdst = vbuf + b0_ld * VSTRIDE + I_DIM + 2 * p_ld;
      const uint32x2* hsrc = ld_base + ((t - 1) & 1) * buf_stride;
      stage_from(spA, spB, hsrc, (unsigned)(t - 1), hdst);
    }
    __syncthreads();   // barrier2: remote h staged

    // ---- phase 2: 6 remote tiles ----
#pragma unroll
    for (int s = 4; s < 10; ++s) {
      int kt = slot_kt(s, mid);
      bf16x8 bv = __builtin_bit_cast(bf16x8, *(const uint32x4*)(vb + kt * 32));
      acc0 = __builtin_amdgcn_mfma_f32_16x16x32_bf16(afrag[0][s], bv, acc0, 0, 0, 0);
      acc1 = __builtin_amdgcn_mfma_f32_16x16x32_bf16(afrag[1][s], bv, acc1, 0, 0, 0);
    }

    // ---- cell fully in registers; own-slice to LDS; tagged pair to global.
    //      Producer-critical path: boost wave priority. ----
    __builtin_amdgcn_s_setprio(1);
    unsigned short* next_own = v_lds[(t + 1) & 1] + batch * VSTRIDE + I_DIM + mid * 64;
#pragma unroll
    for (int rt = 0; rt < 2; ++rt) {
      const f32x4 acc = rt ? acc1 : acc0;
      float c = sigf(acc[1]) * c_reg[rt] + sigf(acc[0]) * tanhfast(acc[2]);
      float h = sigf(acc[3]) * tanhfast(c);
      c_reg[rt] = c; h_keep[rt] = h;
      unsigned short hb16 = f2bf(h);
      next_own[rg * 8 + rt * 4 + quad] = hb16;                    // LDS shortcut (own WG)
      unsigned hb = (unsigned)hb16;
      unsigned partner = (unsigned)__shfl_xor((int)hb, 16, 64);   // col^1, same batch
      if (!(quad & 1)) {
        uint32x2 pv;
        pv[0] = (unsigned)t;                  // tag
        pv[1] = hb | (partner << 16);         // (col, col+1)
        st_pair(st_base + rt * 2 * BATCH_G + (t & 1) * buf_stride, pv);  // fire-and-forget
      }
    }
    __builtin_amdgcn_s_setprio(0);

    // ---- issue NEXT step's speculative poll loads (partner is storing tag t
    //      right about now; by our next phase-1-end the snapshot is fresh) ----
    if (t < T_STEPS && !own_wave) {
      const uint32x2* nsrc = ld_base + (t & 1) * buf_stride;
      asm volatile(
          "global_load_dwordx4 %0, %2, off sc0 sc1\n\t"
          "global_load_dwordx4 %1, %3, off sc0 sc1"
          : "=&v"(spA), "=&v"(spB)
          : "v"(nsrc), "v"(nsrc + 2)
          : "memory");
    }
  }

  // ---- outputs: h_T then c_T, fp32 (pre-bf16-rounding values) ----
#pragma unroll
  for (int rt = 0; rt < 2; ++rt) {
    int gcol = mid * 64 + rg * 8 + rt * 4 + quad;
    long o = (long)(gid * BATCH_G + batch) * H_DIM + gcol;
    out[o]            = h_keep[rt];
    out[OUT_HALF + o] = c_reg[rt];
  }
}

extern "C" void kernel_launch(void* const* d_in, const int* in_sizes, int n_in,
                              void* d_out, int out_size, void* d_ws, size_t ws_size,
                              hipStream_t stream) {
  const float* x    = (const float*)d_in[0];
  const float* W_ih = (const float*)d_in[1];
  const float* W_hh = (const float*)d_in[2];
  const float* b_ih = (const float*)d_in[3];
  const float* b_hh = (const float*)d_in[4];
  float* out = (float*)d_out;

  uint32x2* hbuf = (uint32x2*)d_ws;   // 2 buffers x 64 groups x 128 pairs x 16 batch x 8 B = 2 MB

  // Clear tags so no stale value can match t in [1,336].
  hipMemsetAsync(d_ws, 0, 2u * NGROUP * PAIRS * BATCH_G * 8u, stream);
  lstm_persistent<<<dim3(256), dim3(512), 0, stream>>>(x, W_ih, W_hh, b_ih, b_hh, out, hbuf);
}